// Round 6
// baseline (224.013 us; speedup 1.0000x reference)
//
#include <hip/hip_runtime.h>

// CIN cross-network, fused MFMA implementation (f16 inputs, fp32 accum).
// Round 6: break SIMD phase-lock. (a) launch_bounds(256,2) so the depth-1
// B/xs register pipeline actually fits (round 5 proved (256,3) starved it:
// VGPR stayed 84); (b) per-wave m-loop stagger so co-resident waves issue
// MFMA bursts out of phase (MFMA/VALU pipes overlap across waves, m114);
// (c) v_pk_mul_f16 op_sel broadcast to delete the splat-pack VALU ops.
//
// y[b,n,d] = relu( sum_{m,h} x0[b,m,d] * xk[b,h,d] * W[m,h,n] )
// out[b, 64*l + n] = sum_d y  (per layer l)
//
// Per-wave: 4 private batches; all LDS regions wave-private => NO barriers
// in cin_main.

typedef _Float16 half8 __attribute__((ext_vector_type(8)));
typedef _Float16 half2v __attribute__((ext_vector_type(2)));
typedef float f32x4 __attribute__((ext_vector_type(4)));

#define OUT_STRIDE 192
#define X0R 33            // x0 row stride (f16): 66B -> column reads hit 16
                          // distinct banks (floor((33r+m)/2)%32 injective in r)
#define X0B (16 * X0R)    // 528 f16 per batch
#define XKR 72            // xk row stride: 64 + 8 pad (16B-aligned, 2-way max)
#define XKB 1152          // xk batch stride

// af = av * broadcast(xs.lo) in one VOP3P: lo = av.lo*xs.lo, hi = av.hi*xs.lo.
__device__ __forceinline__ half2v pk_mul_bcast(half2v a, unsigned int xs) {
  half2v r;
  asm("v_pk_mul_f16 %0, %1, %2 op_sel:[0,0] op_sel_hi:[1,0]"
      : "=v"(r) : "v"(a), "v"(xs));
  return r;
}

// ---------------------------------------------------------------------------
// Weight repack (round-4, verified). (m*H+h) == k, so W_flat is [k][n] and the
// source for one 32-k block (kb) is a CONTIGUOUS 8KB tile. Stage via LDS
// (row pad 65), emit fragment order:
//   dst[((kb*4 + t)*64 + lane)*8 + j] = W[k*64 + n],
//   k = kb*32 + (lane>>4)*8 + j,  n = t*16 + (lane&15)
__global__ void prep_w_all(const float* __restrict__ W0,
                           const float* __restrict__ W1,
                           const float* __restrict__ W2,
                           _Float16* __restrict__ dst) {
  __shared__ float tile[32 * 65];
  const int tid = threadIdx.x;
  const int blk = blockIdx.x;
  const float* src;
  _Float16* d;
  int kb;
  if (blk < 32)      { src = W0 + (size_t)blk * 2048;        d = dst;          kb = blk; }
  else if (blk < 96) { src = W1 + (size_t)(blk - 32) * 2048; d = dst + 65536;  kb = blk - 32; }
  else               { src = W2 + (size_t)(blk - 96) * 2048; d = dst + 196608; kb = blk - 96; }
#pragma unroll
  for (int i = tid; i < 2048; i += 256)
    tile[(i >> 6) * 65 + (i & 63)] = src[i];
  __syncthreads();
  const int lane = tid & 63, t = tid >> 6;
  const int qq = lane >> 4, n = t * 16 + (lane & 15);
  half8 v;
#pragma unroll
  for (int j = 0; j < 8; ++j)
    v[j] = (_Float16)tile[(qq * 8 + j) * 65 + n];
  *(half8*)(d + (size_t)kb * 2048 + tid * 8) = v;
}

// ---------------------------------------------------------------------------
// One layer for one wave's 4 private batches, m-loop staggered by mstart and
// software-pipelined depth 1 (ping-pong: exactly 2 live B/xs sets).
// NHI: 32-wide h-blocks (1 for H=32, 2 for H=64). av[b][hi] in registers.
template<int NHI, bool LAST>
__device__ __forceinline__ void run_layer(
    const _Float16* __restrict__ Wp, const half8 (&av)[4][NHI],
    const _Float16* x0row0, _Float16* xkw, float* __restrict__ out,
    long gb0, int loff, int lane, int r, int q, int mstart)
{
  f32x4 acc[4][4];
#pragma unroll
  for (int b = 0; b < 4; ++b)
#pragma unroll
    for (int t = 0; t < 4; ++t) acc[b][t] = (f32x4){0.f, 0.f, 0.f, 0.f};

  const _Float16* Wl = Wp + lane * 8;

  // B fragments for one m: NHI*4 half8 at (m*NHI + hi)*2048 + t*512 (+lane*8).
#define LOADB(DST, MM)                                                      \
  {                                                                         \
    const _Float16* p_ = Wl + (size_t)(MM) * (NHI * 2048);                  \
    _Pragma("unroll")                                                       \
    for (int hi = 0; hi < NHI; ++hi)                                        \
      _Pragma("unroll")                                                     \
      for (int t = 0; t < 4; ++t)                                           \
        DST[hi][t] = *(const half8*)(p_ + hi * 2048 + t * 512);             \
  }

#define LOADXS(DST, MM)                                                     \
  {                                                                         \
    _Pragma("unroll")                                                       \
    for (int b = 0; b < 4; ++b)                                             \
      DST[b] = *(const unsigned short*)(x0row0 + b * X0B + (MM));           \
  }

#define COMPUTE(BB, XX)                                                     \
  {                                                                         \
    _Pragma("unroll")                                                       \
    for (int b = 0; b < 4; ++b) {                                           \
      _Pragma("unroll")                                                     \
      for (int hi = 0; hi < NHI; ++hi) {                                    \
        half8 af;                                                           \
        half2v* ap = (half2v*)&af;                                          \
        const half2v* vp = (const half2v*)&av[b][hi];                       \
        _Pragma("unroll")                                                   \
        for (int j2 = 0; j2 < 4; ++j2)                                      \
          ap[j2] = pk_mul_bcast(vp[j2], XX[b]);                             \
        _Pragma("unroll")                                                   \
        for (int t = 0; t < 4; ++t)                                         \
          acc[b][t] = __builtin_amdgcn_mfma_f32_16x16x32_f16(               \
              af, BB[hi][t], acc[b][t], 0, 0, 0);                           \
      }                                                                     \
    }                                                                       \
  }

  half8 Bc[NHI][4], Bn[NHI][4];
  unsigned int xc[4], xn[4];
  const int m0 = mstart;

  LOADB(Bc, m0);
  LOADXS(xc, m0);

  for (int s = 0; s < 32; s += 2) {
    const int m1 = (m0 + s + 1) & 31;
    LOADB(Bn, m1);
    LOADXS(xn, m1);
    COMPUTE(Bc, xc);
    if (s < 30) {
      const int m2 = (m0 + s + 2) & 31;
      LOADB(Bc, m2);
      LOADXS(xc, m2);
    }
    COMPUTE(Bn, xn);
  }
#undef LOADB
#undef LOADXS
#undef COMPUTE

  // Epilogue (round-1 verified). C/D layout: col n = r, row d = q*4 + reg.
#pragma unroll
  for (int b = 0; b < 4; ++b) {
#pragma unroll
    for (int t = 0; t < 4; ++t) {
      float s = 0.f;
#pragma unroll
      for (int rr = 0; rr < 4; ++rr) {
        float v = acc[b][t][rr];
        v = v > 0.f ? v : 0.f;
        s += v;
        if (!LAST)
          xkw[b * XKB + (q * 4 + rr) * XKR + t * 16 + r] = (_Float16)v;
      }
      s += __shfl_xor(s, 16);
      s += __shfl_xor(s, 32);
      if (q == 0)
        out[(gb0 + b) * OUT_STRIDE + loff + t * 16 + r] = s;
    }
  }
}

__global__ __launch_bounds__(256, 2) void cin_main(
    const float* __restrict__ emb, const _Float16* __restrict__ Wall,
    float* __restrict__ out)
{
  // x0: 16 batches * 528 f16 (16 d rows of stride 33) = 16896 B
  // xk: 16 batches * 1152 f16 (16 d rows of stride 72) = 36864 B
  // total 53760 B; 2 blocks/CU (reg-bound by design: depth-1 pipeline).
  __shared__ __align__(16) _Float16 lds[16 * X0B + 16 * XKB];
  const int lane = threadIdx.x & 63;
  const int wv = threadIdx.x >> 6;
  const int r = lane & 15, q = lane >> 4;
  const long gb0 = (long)blockIdx.x * 16 + wv * 4;

  // Phase stagger: co-resident waves on a SIMD share wv (one per block), so
  // mix blockIdx in; K-sum is commutative so any rotation is correct.
  const int mstart = ((blockIdx.x + wv) & 3) * 8;

  _Float16* x0w = &lds[wv * 4 * X0B];
  _Float16* xkw = &lds[16 * X0B + wv * 4 * XKB];

  // Stage this wave's 4 batches: read (m,d) fp32, write transposed (d,m) f16.
#pragma unroll
  for (int bb = 0; bb < 4; ++bb) {
    const float* src = emb + (gb0 + bb) * 512;
    _Float16* dstb = x0w + bb * X0B;
#pragma unroll
    for (int i = 0; i < 2; ++i) {
      int f = i * 256 + lane * 4;         // flat = m*16 + d, d aligned to 4
      float4 v = *(const float4*)(src + f);
      int m = f >> 4, d = f & 15;
      dstb[(d + 0) * X0R + m] = (_Float16)v.x;
      dstb[(d + 1) * X0R + m] = (_Float16)v.y;
      dstb[(d + 2) * X0R + m] = (_Float16)v.z;
      dstb[(d + 3) * X0R + m] = (_Float16)v.w;
    }
  }
  // All LDS regions are wave-private: program order + waitcnt suffice.

  const _Float16* x0row0 = x0w + r * X0R;

  // Layer 1: A-vectors av1[b][j] = x0[m=q*8+j, d=r] (8 scalar reads, one-time;
  // stride-33 rows are only 2B-aligned so no vector load here).
  half8 av1[4][1];
#pragma unroll
  for (int b = 0; b < 4; ++b)
#pragma unroll
    for (int j = 0; j < 8; ++j)
      av1[b][0][j] = x0row0[b * X0B + q * 8 + j];
  run_layer<1, false>(Wall, av1, x0row0, xkw, out, gb0, 0, lane, r, q, mstart);

  // Layer 2: A-vectors from xk (h = hi*32 + q*8 + j), 16B-aligned b128 loads.
  half8 av2[4][2];
#pragma unroll
  for (int b = 0; b < 4; ++b)
#pragma unroll
    for (int hi = 0; hi < 2; ++hi)
      av2[b][hi] = *(const half8*)(xkw + b * XKB + r * XKR + hi * 32 + q * 8);
  run_layer<2, false>(Wall + 65536, av2, x0row0, xkw, out, gb0, 64, lane, r, q, mstart);

  // Layer 3: reload A-vectors (layer 2 rewrote xk).
#pragma unroll
  for (int b = 0; b < 4; ++b)
#pragma unroll
    for (int hi = 0; hi < 2; ++hi)
      av2[b][hi] = *(const half8*)(xkw + b * XKB + r * XKR + hi * 32 + q * 8);
  run_layer<2, true>(Wall + 196608, av2, x0row0, xkw, out, gb0, 128, lane, r, q, mstart);
}

extern "C" void kernel_launch(void* const* d_in, const int* in_sizes, int n_in,
                              void* d_out, int out_size, void* d_ws, size_t ws_size,
                              hipStream_t stream) {
  const float* emb = (const float*)d_in[0];
  const float* W0  = (const float*)d_in[1];
  const float* W1  = (const float*)d_in[2];
  const float* W2  = (const float*)d_in[3];
  float* out = (float*)d_out;
  _Float16* ws = (_Float16*)d_ws;   // needs 327680 f16 = 640 KB

  // Weight repack: one block per 32-k block (32 + 64 + 64 = 160 blocks).
  prep_w_all<<<160, 256, 0, stream>>>(W0, W1, W2, ws);

  // 16384 batches / 16 per block = 1024 blocks of 256 threads (4 waves x 4 b).
  cin_main<<<1024, 256, 0, stream>>>(emb, ws, out);
}